// Round 2
// baseline (1234.211 us; speedup 1.0000x reference)
//
#include <hip/hip_runtime.h>
#include <hip/hip_bf16.h>
#include <stdint.h>

typedef unsigned short u16;
typedef u16 u16x8 __attribute__((ext_vector_type(8)));

#define SCALE 0.17677669529663689f
#define EPS 1e-5f

static __device__ __forceinline__ float b2f(u16 u){
  union { uint32_t i; float f; } cv; cv.i = ((uint32_t)u) << 16; return cv.f;
}
static __device__ __forceinline__ u16 f2b(float f){
  uint32_t u = __float_as_uint(f);
  uint32_t r = (u + 0x7FFFu + ((u >> 16) & 1u)) >> 16;
  return (u16)r;
}

// ---- K1: depthwise 3x3 Q conv (64x64 spatial, SAME, NHWC); fp32 in, bf16 out ----
__global__ __launch_bounds__(256) void k_qconv(const float* __restrict__ x,
                                               const float* __restrict__ w,
                                               u16* __restrict__ q){
  const int c = threadIdx.x;
  const int blk = blockIdx.x;        // b*4096 + n
  const int b = blk >> 12, n = blk & 4095;
  const int y = n >> 6, xw = n & 63;
  float wv[9];
#pragma unroll
  for (int t = 0; t < 9; ++t) wv[t] = w[c*9 + t];
  float acc = 0.f;
#pragma unroll
  for (int ky = 0; ky < 3; ++ky){
    const int yy = y + ky - 1;
    if ((unsigned)yy >= 64u) continue;
#pragma unroll
    for (int kx = 0; kx < 3; ++kx){
      const int xx = xw + kx - 1;
      if ((unsigned)xx >= 64u) continue;
      acc += x[(((b<<12) + (yy<<6) + xx) << 8) + c] * wv[ky*3 + kx];
    }
  }
  q[(blk << 8) + c] = f2b(acc);
}

// ---- K2: stride-2 2x2 dense conv (C=256 -> 256, K=1024) + bias + LayerNorm ----
// block = 4 output positions; thread = one output channel
__global__ __launch_bounds__(256) void k_srln(const float* __restrict__ x,
                                              const float* __restrict__ srw,
                                              const float* __restrict__ srb,
                                              const float* __restrict__ lng,
                                              const float* __restrict__ lnb,
                                              float* __restrict__ lnxr){
  __shared__ float patch[4096];      // [(j*4+p)*256 + ci]
  __shared__ float red[2][4][4];     // [sum|sumsq][j][wave]
  const int c = threadIdx.x;
  const int blk = blockIdx.x;        // b*256 + group
  const int b = blk >> 8;
  const int nk0 = (blk & 255) << 2;
#pragma unroll
  for (int j = 0; j < 4; ++j){
    const int nk = nk0 + j;
    const int hs = nk >> 5, wsp = nk & 31;
#pragma unroll
    for (int p = 0; p < 4; ++p){
      const int y = 2*hs + (p>>1), xg = 2*wsp + (p&1);
      patch[(j*4+p)*256 + c] = x[(((b<<12) + (y<<6) + xg) << 8) + c];
    }
  }
  __syncthreads();
  const float bias = srb[c];
  float acc[4] = {bias, bias, bias, bias};
  const float* wrow = srw + c*1024;  // [co][ci][ky][kx] row for co=c
  for (int ci = 0; ci < 256; ci += 2){
    const float4 wa = *reinterpret_cast<const float4*>(wrow + (ci<<2));
    const float4 wb = *reinterpret_cast<const float4*>(wrow + (ci<<2) + 4);
#pragma unroll
    for (int j = 0; j < 4; ++j){
      const int base = j*1024 + ci;
      float a = acc[j];
      a += patch[base      ] * wa.x;
      a += patch[base + 256] * wa.y;
      a += patch[base + 512] * wa.z;
      a += patch[base + 768] * wa.w;
      a += patch[base +   1] * wb.x;
      a += patch[base + 257] * wb.y;
      a += patch[base + 513] * wb.z;
      a += patch[base + 769] * wb.w;
      acc[j] = a;
    }
  }
  const int lane = c & 63, wid = c >> 6;
#pragma unroll
  for (int j = 0; j < 4; ++j){
    float v = acc[j], vv = acc[j]*acc[j];
#pragma unroll
    for (int off = 32; off; off >>= 1){
      v  += __shfl_xor(v, off);
      vv += __shfl_xor(vv, off);
    }
    if (lane == 0){ red[0][j][wid] = v; red[1][j][wid] = vv; }
  }
  __syncthreads();
  const float gg = lng[c], bb = lnb[c];
#pragma unroll
  for (int j = 0; j < 4; ++j){
    const float s  = red[0][j][0] + red[0][j][1] + red[0][j][2] + red[0][j][3];
    const float sq = red[1][j][0] + red[1][j][1] + red[1][j][2] + red[1][j][3];
    const float mu = s * (1.f/256.f);
    const float var = sq * (1.f/256.f) - mu*mu;
    const float inv = rsqrtf(var + EPS);
    lnxr[((b<<10) + nk0 + j)*256 + c] = (acc[j] - mu) * inv * gg + bb;
  }
}

// ---- K3: depthwise 3x3 KV conv (32x32, SAME); writes kT/vT [b,h,d,Nk] bf16 ----
// jax grouped conv: out channel o uses input channel o>>1, kernel row o
__global__ __launch_bounds__(512) void k_kvconv(const float* __restrict__ lnxr,
                                                const float* __restrict__ w,
                                                u16* __restrict__ kT,
                                                u16* __restrict__ vT){
  const int o = threadIdx.x;         // 0..511
  const int blk = blockIdx.x;        // b*1024 + nk
  const int b = blk >> 10, nk = blk & 1023;
  const int y = nk >> 5, xw = nk & 31;
  const int g = o >> 1;
  float wv[9];
#pragma unroll
  for (int t = 0; t < 9; ++t) wv[t] = w[o*9 + t];
  float acc = 0.f;
#pragma unroll
  for (int ky = 0; ky < 3; ++ky){
    const int yy = y + ky - 1;
    if ((unsigned)yy >= 32u) continue;
#pragma unroll
    for (int kx = 0; kx < 3; ++kx){
      const int xx = xw + kx - 1;
      if ((unsigned)xx >= 32u) continue;
      acc += lnxr[(((b<<10) + (yy<<5) + xx) << 8) + g] * wv[ky*3 + kx];
    }
  }
  const int t = o & 255;
  const int h = t >> 5, dd = t & 31;
  u16* dst = (o < 256) ? kT : vT;
  dst[((((b<<3) + h) << 5) + dd) * 1024 + nk] = f2b(acc);
}

// ---- K4: fused attention, one wave per query row; lane owns 16 consecutive keys ----
__global__ __launch_bounds__(256) void k_attn(const u16* __restrict__ q,
                                              const u16* __restrict__ kT,
                                              const u16* __restrict__ vT,
                                              float* __restrict__ att){
  const int lane = threadIdx.x & 63;
  const int row = (blockIdx.x << 2) + (threadIdx.x >> 6);  // b*32768 + h*4096 + n
  const int b = row >> 15;
  const int rem = row & 32767;
  const int h = rem >> 12, n = rem & 4095;
  const u16* qp = q + (((b<<12) + n) << 8) + (h << 5);
  float qf[32];
#pragma unroll
  for (int t = 0; t < 4; ++t){
    const u16x8 qv = *reinterpret_cast<const u16x8*>(qp + t*8);
#pragma unroll
    for (int u = 0; u < 8; ++u) qf[t*8+u] = b2f(qv[u]);
  }
  const int slab = (((b<<3) + h) << 15) + (lane << 4);
  const u16* kb = kT + slab;
  const u16* vb = vT + slab;
  float s[16];
#pragma unroll
  for (int t = 0; t < 16; ++t) s[t] = 0.f;
#pragma unroll
  for (int dd = 0; dd < 32; ++dd){
    const u16x8 k0 = *reinterpret_cast<const u16x8*>(kb + (dd<<10));
    const u16x8 k1 = *reinterpret_cast<const u16x8*>(kb + (dd<<10) + 8);
    const float qv = qf[dd];
#pragma unroll
    for (int u = 0; u < 8; ++u){
      s[u]   += qv * b2f(k0[u]);
      s[u+8] += qv * b2f(k1[u]);
    }
  }
  float m = -1e30f;
#pragma unroll
  for (int t = 0; t < 16; ++t){ s[t] *= SCALE; m = fmaxf(m, s[t]); }
#pragma unroll
  for (int off = 32; off; off >>= 1) m = fmaxf(m, __shfl_xor(m, off));
  float sum = 0.f;
#pragma unroll
  for (int t = 0; t < 16; ++t){ s[t] = __expf(s[t] - m); sum += s[t]; }
#pragma unroll
  for (int off = 32; off; off >>= 1) sum += __shfl_xor(sum, off);
  float acc[32];
#pragma unroll
  for (int dd = 0; dd < 32; ++dd){
    const u16x8 v0 = *reinterpret_cast<const u16x8*>(vb + (dd<<10));
    const u16x8 v1 = *reinterpret_cast<const u16x8*>(vb + (dd<<10) + 8);
    float a = 0.f;
#pragma unroll
    for (int u = 0; u < 8; ++u){
      a += s[u]   * b2f(v0[u]);
      a += s[u+8] * b2f(v1[u]);
    }
    acc[dd] = a;
  }
#pragma unroll
  for (int dd = 0; dd < 32; ++dd){
    float a = acc[dd];
#pragma unroll
    for (int off = 32; off; off >>= 1) a += __shfl_xor(a, off);
    acc[dd] = a;
  }
  if (lane == 0){
    const float inv = 1.f / sum;
    float* op = att + (((b<<12) + n) << 8) + (h << 5);
#pragma unroll
    for (int dd = 0; dd < 32; ++dd) op[dd] = acc[dd] * inv;
  }
}

// ---- K5: out = att @ proj_w^T + proj_b (all fp32) ----
__global__ __launch_bounds__(256) void k_proj(const float* __restrict__ att,
                                              const float* __restrict__ pw,
                                              const float* __restrict__ pb,
                                              float* __restrict__ out){
  __shared__ float rowbuf[4][256];
  const int c = threadIdx.x;
  const int blk = blockIdx.x;       // b*1024 + group
  const int b = blk >> 10;
  const int n0 = (blk & 1023) << 2;
#pragma unroll
  for (int j = 0; j < 4; ++j)
    rowbuf[j][c] = att[(((b<<12) + n0 + j) << 8) + c];
  __syncthreads();
  const float bias = pb[c];
  float acc[4] = {bias, bias, bias, bias};
  const float* wrow = pw + (c << 8);
  for (int ci = 0; ci < 256; ci += 4){
    const float4 wv = *reinterpret_cast<const float4*>(wrow + ci);
#pragma unroll
    for (int j = 0; j < 4; ++j){
      float a = acc[j];
      a += rowbuf[j][ci  ] * wv.x;
      a += rowbuf[j][ci+1] * wv.y;
      a += rowbuf[j][ci+2] * wv.z;
      a += rowbuf[j][ci+3] * wv.w;
      acc[j] = a;
    }
  }
#pragma unroll
  for (int j = 0; j < 4; ++j)
    out[(((b<<12) + n0 + j) << 8) + c] = acc[j];
}

extern "C" void kernel_launch(void* const* d_in, const int* in_sizes, int n_in,
                              void* d_out, int out_size, void* d_ws, size_t ws_size,
                              hipStream_t stream){
  const float* x   = (const float*)d_in[0];
  const float* qw  = (const float*)d_in[1];
  const float* kvw = (const float*)d_in[2];
  const float* srw = (const float*)d_in[3];
  const float* srb = (const float*)d_in[4];
  const float* lng = (const float*)d_in[5];
  const float* lnb = (const float*)d_in[6];
  const float* pw  = (const float*)d_in[7];
  const float* pb  = (const float*)d_in[8];
  float* out = (float*)d_out;

  char* ws = (char*)d_ws;
  u16*   qbuf = (u16*)(ws);                   // 8,388,608 B  [B,N,C] bf16
  float* lnxr = (float*)(ws + 8388608);       // 4,194,304 B  [B,Nk,C] f32
  u16*   kT   = (u16*)(ws + 12582912);        // 2,097,152 B  [B,h,d,Nk] bf16
  u16*   vT   = (u16*)(ws + 14680064);        // 2,097,152 B  [B,h,d,Nk] bf16
  float* att  = (float*)(ws + 16777216);      // 16,777,216 B [B,N,C] f32
  // total ws use: 32 MiB

  hipLaunchKernelGGL(k_qconv,  dim3(16384), dim3(256), 0, stream, x, qw, qbuf);
  hipLaunchKernelGGL(k_srln,   dim3(1024),  dim3(256), 0, stream, x, srw, srb, lng, lnb, lnxr);
  hipLaunchKernelGGL(k_kvconv, dim3(4096),  dim3(512), 0, stream, lnxr, kvw, kT, vT);
  hipLaunchKernelGGL(k_attn,   dim3(32768), dim3(256), 0, stream, qbuf, kT, vT, att);
  hipLaunchKernelGGL(k_proj,   dim3(4096),  dim3(256), 0, stream, att, pw, pb, out);
}

// Round 3
// 423.498 us; speedup vs baseline: 2.9143x; 2.9143x over previous
//
#include <hip/hip_runtime.h>
#include <stdint.h>

typedef unsigned short u16;
typedef short s16x8 __attribute__((ext_vector_type(8)));
typedef short s16x4 __attribute__((ext_vector_type(4)));
typedef float f32x4 __attribute__((ext_vector_type(4)));

#define SCALE 0.17677669529663689f
#define LOG2E 1.4426950408889634f
#define QS (SCALE * LOG2E)
#define EPS 1e-5f

static __device__ __forceinline__ u16 f2b(float f){   // RNE
  uint32_t u = __float_as_uint(f);
  uint32_t r = (u + 0x7FFFu + ((u >> 16) & 1u)) >> 16;
  return (u16)r;
}
static __device__ __forceinline__ short f2bq(float f){ // round-half-up (P>=0)
  return (short)((__float_as_uint(f) + 0x8000u) >> 16);
}

// ---- K1: depthwise 3x3 Q conv; fp32 in, bf16 out, pre-scaled by SCALE*log2e ----
__global__ __launch_bounds__(256) void k_qconv(const float* __restrict__ x,
                                               const float* __restrict__ w,
                                               u16* __restrict__ q){
  const int c = threadIdx.x;
  const int blk = blockIdx.x;        // b*4096 + n
  const int b = blk >> 12, n = blk & 4095;
  const int y = n >> 6, xw = n & 63;
  float wv[9];
#pragma unroll
  for (int t = 0; t < 9; ++t) wv[t] = w[c*9 + t];
  float acc = 0.f;
#pragma unroll
  for (int ky = 0; ky < 3; ++ky){
    const int yy = y + ky - 1;
    if ((unsigned)yy >= 64u) continue;
#pragma unroll
    for (int kx = 0; kx < 3; ++kx){
      const int xx = xw + kx - 1;
      if ((unsigned)xx >= 64u) continue;
      acc += x[(((b<<12) + (yy<<6) + xx) << 8) + c] * wv[ky*3 + kx];
    }
  }
  q[(blk << 8) + c] = f2b(acc * QS);
}

// ---- K2: stride-2 2x2 dense conv (C=256->256) + bias + LayerNorm ----
__global__ __launch_bounds__(256) void k_srln(const float* __restrict__ x,
                                              const float* __restrict__ srw,
                                              const float* __restrict__ srb,
                                              const float* __restrict__ lng,
                                              const float* __restrict__ lnb,
                                              float* __restrict__ lnxr){
  __shared__ float patch[4096];
  __shared__ float red[2][4][4];
  const int c = threadIdx.x;
  const int blk = blockIdx.x;        // b*256 + group
  const int b = blk >> 8;
  const int nk0 = (blk & 255) << 2;
#pragma unroll
  for (int j = 0; j < 4; ++j){
    const int nk = nk0 + j;
    const int hs = nk >> 5, wsp = nk & 31;
#pragma unroll
    for (int p = 0; p < 4; ++p){
      const int y = 2*hs + (p>>1), xg = 2*wsp + (p&1);
      patch[(j*4+p)*256 + c] = x[(((b<<12) + (y<<6) + xg) << 8) + c];
    }
  }
  __syncthreads();
  const float bias = srb[c];
  float acc[4] = {bias, bias, bias, bias};
  const float* wrow = srw + c*1024;
  for (int ci = 0; ci < 256; ci += 2){
    const float4 wa = *reinterpret_cast<const float4*>(wrow + (ci<<2));
    const float4 wb = *reinterpret_cast<const float4*>(wrow + (ci<<2) + 4);
#pragma unroll
    for (int j = 0; j < 4; ++j){
      const int base = j*1024 + ci;
      float a = acc[j];
      a += patch[base      ] * wa.x;
      a += patch[base + 256] * wa.y;
      a += patch[base + 512] * wa.z;
      a += patch[base + 768] * wa.w;
      a += patch[base +   1] * wb.x;
      a += patch[base + 257] * wb.y;
      a += patch[base + 513] * wb.z;
      a += patch[base + 769] * wb.w;
      acc[j] = a;
    }
  }
  const int lane = c & 63, wid = c >> 6;
#pragma unroll
  for (int j = 0; j < 4; ++j){
    float v = acc[j], vv = acc[j]*acc[j];
#pragma unroll
    for (int off = 32; off; off >>= 1){
      v  += __shfl_xor(v, off);
      vv += __shfl_xor(vv, off);
    }
    if (lane == 0){ red[0][j][wid] = v; red[1][j][wid] = vv; }
  }
  __syncthreads();
  const float gg = lng[c], bb = lnb[c];
#pragma unroll
  for (int j = 0; j < 4; ++j){
    const float s  = red[0][j][0] + red[0][j][1] + red[0][j][2] + red[0][j][3];
    const float sq = red[1][j][0] + red[1][j][1] + red[1][j][2] + red[1][j][3];
    const float mu = s * (1.f/256.f);
    const float var = sq * (1.f/256.f) - mu*mu;
    const float inv = rsqrtf(var + EPS);
    lnxr[((b<<10) + nk0 + j)*256 + c] = (acc[j] - mu) * inv * gg + bb;
  }
}

// ---- K3: depthwise 3x3 KV conv; K row-major [b,h,nk,32], V transposed [b,h,32,Nk] ----
__global__ __launch_bounds__(512) void k_kvconv(const float* __restrict__ lnxr,
                                                const float* __restrict__ w,
                                                u16* __restrict__ kbuf,
                                                u16* __restrict__ vT){
  const int o = threadIdx.x;         // 0..511
  const int blk = blockIdx.x;        // b*1024 + nk
  const int b = blk >> 10, nk = blk & 1023;
  const int y = nk >> 5, xw = nk & 31;
  const int g = o >> 1;
  float wv[9];
#pragma unroll
  for (int t = 0; t < 9; ++t) wv[t] = w[o*9 + t];
  float acc = 0.f;
#pragma unroll
  for (int ky = 0; ky < 3; ++ky){
    const int yy = y + ky - 1;
    if ((unsigned)yy >= 32u) continue;
#pragma unroll
    for (int kx = 0; kx < 3; ++kx){
      const int xx = xw + kx - 1;
      if ((unsigned)xx >= 32u) continue;
      acc += lnxr[(((b<<10) + (yy<<5) + xx) << 8) + g] * wv[ky*3 + kx];
    }
  }
  const int t = o & 255;
  const int h = t >> 5, dd = t & 31;
  const u16 val = f2b(acc);
  if (o < 256){
    kbuf[(((((b<<3) + h) << 10) + nk) << 5) + dd] = val;     // [bh][nk][d]
  } else {
    vT[(((((b<<3) + h) << 5) + dd) << 10) + nk] = val;       // [bh][d][Nk]
  }
}

// ---- K4: MFMA flash attention. One wave per 16-query tile; swapped QK^T. ----
// Q pre-scaled by SCALE*log2e -> P = exp2(S). No LDS, no barriers.
__global__ __launch_bounds__(256) void k_attn(const u16* __restrict__ q,
                                              const u16* __restrict__ kbuf,
                                              const u16* __restrict__ vT,
                                              float* __restrict__ att){
  const int l = threadIdx.x & 63;
  const int w = (blockIdx.x << 2) + (threadIdx.x >> 6);
  const int bh = w >> 8, qt = w & 255;        // 256 q-tiles per (b,h)
  const int b = bh >> 3, h = bh & 7;
  const int r15 = l & 15, g = l >> 4;

  // Q fragment: B-frag of S^T = K*Q^T: lane holds Q[q=r15][d=8g..8g+7]
  const s16x8 qfrag = *reinterpret_cast<const s16x8*>(
      q + (((b<<12) + (qt<<4) + r15) << 8) + (h<<5) + (g<<3));

  const u16* kb = kbuf + (bh<<15) + r15*32 + (g<<3);
  const u16* vb = vT + (bh<<15);

  f32x4 acc0 = {0.f,0.f,0.f,0.f};
  f32x4 acc1 = {0.f,0.f,0.f,0.f};
  const f32x4 zero = {0.f,0.f,0.f,0.f};
  float lsum = 0.f;

  for (int kv0 = 0; kv0 < 1024; kv0 += 64){
    // S^T tiles: 4 subtiles of 16 keys; lane holds S^T[key=st*16+4g+r][q=r15]
    f32x4 s[4];
#pragma unroll
    for (int st = 0; st < 4; ++st){
      const s16x8 kf = *reinterpret_cast<const s16x8*>(kb + ((kv0 + (st<<4)) << 5));
      s[st] = __builtin_amdgcn_mfma_f32_16x16x32_bf16(kf, qfrag, zero, 0, 0, 0);
    }
    // softmax numerator (no max subtraction; scores pre-scaled, bounded)
    float p[4][4];
    float ps = 0.f;
#pragma unroll
    for (int st = 0; st < 4; ++st)
#pragma unroll
      for (int r = 0; r < 4; ++r){
        const float e = exp2f(s[st][r]);
        p[st][r] = e;
        ps += e;
      }
    ps += __shfl_xor(ps, 16);
    ps += __shfl_xor(ps, 32);
    lsum += ps;
    // pack P: pf[pr] covers keys kv0+32*pr .. +31; elem j<4 from st=2pr (key 4g+j),
    // j>=4 from st=2pr+1 (key 16+4g+j-4) — matches V B-frag load pattern below
    s16x8 pf0, pf1;
#pragma unroll
    for (int j = 0; j < 4; ++j){
      pf0[j]   = f2bq(p[0][j]);
      pf0[j+4] = f2bq(p[1][j]);
      pf1[j]   = f2bq(p[2][j]);
      pf1[j+4] = f2bq(p[3][j]);
    }
#pragma unroll
    for (int pr = 0; pr < 2; ++pr){
      const s16x8 pfr = pr ? pf1 : pf0;
      const int kvp = kv0 + (pr << 5);
#pragma unroll
      for (int h2 = 0; h2 < 2; ++h2){
        const u16* vrow = vb + (((h2<<4) + r15) << 10) + kvp + (g<<2);
        const s16x4 v0 = *reinterpret_cast<const s16x4*>(vrow);
        const s16x4 v1 = *reinterpret_cast<const s16x4*>(vrow + 16);
        s16x8 vf;
        vf[0]=v0[0]; vf[1]=v0[1]; vf[2]=v0[2]; vf[3]=v0[3];
        vf[4]=v1[0]; vf[5]=v1[1]; vf[6]=v1[2]; vf[7]=v1[3];
        if (h2 == 0)
          acc0 = __builtin_amdgcn_mfma_f32_16x16x32_bf16(pfr, vf, acc0, 0, 0, 0);
        else
          acc1 = __builtin_amdgcn_mfma_f32_16x16x32_bf16(pfr, vf, acc1, 0, 0, 0);
      }
    }
  }
  const float linv = 1.f / lsum;                 // lane holds total for q=r15
#pragma unroll
  for (int r = 0; r < 4; ++r){
    const float fl = __shfl(linv, (g<<2) + r);   // PV D row q = 4g+r
    const int n = (qt<<4) + (g<<2) + r;
    float* orow = att + (((b<<12) + n) << 8) + (h<<5) + r15;
    orow[0]  = acc0[r] * fl;
    orow[16] = acc1[r] * fl;
  }
}

// ---- K5: out = att @ proj_w^T + proj_b ----
__global__ __launch_bounds__(256) void k_proj(const float* __restrict__ att,
                                              const float* __restrict__ pw,
                                              const float* __restrict__ pb,
                                              float* __restrict__ out){
  __shared__ float rowbuf[4][256];
  const int c = threadIdx.x;
  const int blk = blockIdx.x;
  const int b = blk >> 10;
  const int n0 = (blk & 1023) << 2;
#pragma unroll
  for (int j = 0; j < 4; ++j)
    rowbuf[j][c] = att[(((b<<12) + n0 + j) << 8) + c];
  __syncthreads();
  const float bias = pb[c];
  float acc[4] = {bias, bias, bias, bias};
  const float* wrow = pw + (c << 8);
  for (int ci = 0; ci < 256; ci += 4){
    const float4 wv = *reinterpret_cast<const float4*>(wrow + ci);
#pragma unroll
    for (int j = 0; j < 4; ++j){
      float a = acc[j];
      a += rowbuf[j][ci  ] * wv.x;
      a += rowbuf[j][ci+1] * wv.y;
      a += rowbuf[j][ci+2] * wv.z;
      a += rowbuf[j][ci+3] * wv.w;
      acc[j] = a;
    }
  }
#pragma unroll
  for (int j = 0; j < 4; ++j)
    out[(((b<<12) + n0 + j) << 8) + c] = acc[j];
}

extern "C" void kernel_launch(void* const* d_in, const int* in_sizes, int n_in,
                              void* d_out, int out_size, void* d_ws, size_t ws_size,
                              hipStream_t stream){
  const float* x   = (const float*)d_in[0];
  const float* qw  = (const float*)d_in[1];
  const float* kvw = (const float*)d_in[2];
  const float* srw = (const float*)d_in[3];
  const float* srb = (const float*)d_in[4];
  const float* lng = (const float*)d_in[5];
  const float* lnb = (const float*)d_in[6];
  const float* pw  = (const float*)d_in[7];
  const float* pb  = (const float*)d_in[8];
  float* out = (float*)d_out;

  char* ws = (char*)d_ws;
  u16*   qbuf = (u16*)(ws);                   // 8 MiB  [B,N,C] bf16 (pre-scaled)
  float* lnxr = (float*)(ws + 8388608);       // 4 MiB  [B,Nk,C] f32
  u16*   kbuf = (u16*)(ws + 12582912);        // 2 MiB  [B,h,Nk,d] bf16
  u16*   vT   = (u16*)(ws + 14680064);        // 2 MiB  [B,h,d,Nk] bf16
  float* att  = (float*)(ws + 16777216);      // 16 MiB [B,N,C] f32

  hipLaunchKernelGGL(k_qconv,  dim3(16384), dim3(256), 0, stream, x, qw, qbuf);
  hipLaunchKernelGGL(k_srln,   dim3(1024),  dim3(256), 0, stream, x, srw, srb, lng, lnb, lnxr);
  hipLaunchKernelGGL(k_kvconv, dim3(4096),  dim3(512), 0, stream, lnxr, kvw, kbuf, vT);
  hipLaunchKernelGGL(k_attn,   dim3(2048),  dim3(256), 0, stream, qbuf, kbuf, vT, att);
  hipLaunchKernelGGL(k_proj,   dim3(4096),  dim3(256), 0, stream, att, pw, pb, out);
}

// Round 4
// 132.975 us; speedup vs baseline: 9.2815x; 3.1848x over previous
//
#include <hip/hip_runtime.h>
#include <stdint.h>

typedef unsigned short u16;
typedef short s16x8 __attribute__((ext_vector_type(8)));
typedef short s16x4 __attribute__((ext_vector_type(4)));
typedef float f32x4 __attribute__((ext_vector_type(4)));

#define SCALE 0.17677669529663689f
#define LOG2E 1.4426950408889634f
#define QS (SCALE * LOG2E)
#define EPS 1e-5f

static __device__ __forceinline__ float b2f(u16 u){
  union { uint32_t i; float f; } cv; cv.i = ((uint32_t)u) << 16; return cv.f;
}
static __device__ __forceinline__ u16 f2b(float f){   // RNE
  uint32_t u = __float_as_uint(f);
  uint32_t r = (u + 0x7FFFu + ((u >> 16) & 1u)) >> 16;
  return (u16)r;
}
static __device__ __forceinline__ short f2bq(float f){ // round-half-up (P>=0)
  return (short)((__float_as_uint(f) + 0x8000u) >> 16);
}

// ---- K0: repack srw -> wsr [k/8][co][8] bf16 (k=p*256+ci), pw -> wpj same scheme (k=ci) ----
__global__ __launch_bounds__(256) void k_prep(const float* __restrict__ srw,
                                              const float* __restrict__ pw,
                                              u16* __restrict__ wsr,
                                              u16* __restrict__ wpj){
  const int t = blockIdx.x*256 + threadIdx.x;
  if (t < 262144){
    const int co = t >> 10, k = t & 1023;
    const float v = srw[(co<<10) + ((k&255)<<2) + (k>>8)];   // [co][ci][p] with p=k>>8
    wsr[((((k>>3)<<8) + co)<<3) + (k&7)] = f2b(v);
  } else if (t < 327680){
    const int u2 = t - 262144;
    const int co = u2 >> 8, k = u2 & 255;
    wpj[((((k>>3)<<8) + co)<<3) + (k&7)] = f2b(pw[(co<<8) + k]);
  }
}

// ---- K1: depthwise 3x3 Q conv; also emits bf16 copy of x. Q pre-scaled by SCALE*log2e ----
__global__ __launch_bounds__(256) void k_qconv(const float* __restrict__ x,
                                               const float* __restrict__ w,
                                               u16* __restrict__ q,
                                               u16* __restrict__ xbf){
  const int c = threadIdx.x;
  const int blk = blockIdx.x;        // b*4096 + n
  const int b = blk >> 12, n = blk & 4095;
  const int y = n >> 6, xw = n & 63;
  float wv[9];
#pragma unroll
  for (int t = 0; t < 9; ++t) wv[t] = w[c*9 + t];
  float acc = 0.f;
#pragma unroll
  for (int ky = 0; ky < 3; ++ky){
    const int yy = y + ky - 1;
    if ((unsigned)yy >= 64u) continue;
#pragma unroll
    for (int kx = 0; kx < 3; ++kx){
      const int xx = xw + kx - 1;
      if ((unsigned)xx >= 64u) continue;
      const float xv = x[(((b<<12) + (yy<<6) + xx) << 8) + c];
      acc += xv * wv[ky*3 + kx];
    }
  }
  q[(blk << 8) + c] = f2b(acc * QS);
  xbf[(blk << 8) + c] = f2b(x[(blk << 8) + c]);
}

// ---- K2: SR conv as MFMA GEMM (M=4096,N=256,K=1024) + bias + fused LayerNorm ----
__global__ __launch_bounds__(256) void k_srgemm(const u16* __restrict__ xbf,
                                                const u16* __restrict__ wsr,
                                                const float* __restrict__ srb,
                                                const float* __restrict__ lng,
                                                const float* __restrict__ lnb,
                                                float* __restrict__ lnxr){
  __shared__ float red_s[16][4], red_q[16][4];
  __shared__ float mu_s[16], rs_s[16];
  const int tid = threadIdx.x;
  const int l = tid & 63, w = tid >> 6;
  const int r15 = l & 15, g = l >> 4;
  const int m0 = blockIdx.x << 4;            // 16 rows of im2col
  const int ma = m0 + r15;                   // A-frag row
  const int bb_ = ma >> 10, nk = ma & 1023;
  const int hs = nk >> 5, wsx = nk & 31;
  int pixbase[4];
#pragma unroll
  for (int p = 0; p < 4; ++p){
    const int y = 2*hs + (p>>1), xx = 2*wsx + (p&1);
    pixbase[p] = (((bb_<<12) + (y<<6) + xx) << 8);
  }
  f32x4 acc[4];
#pragma unroll
  for (int i = 0; i < 4; ++i) acc[i] = (f32x4){0.f,0.f,0.f,0.f};
  for (int ks = 0; ks < 32; ++ks){
    const s16x8 af = *reinterpret_cast<const s16x8*>(
        xbf + pixbase[ks>>3] + ((ks&7)<<5) + (g<<3));
#pragma unroll
    for (int i = 0; i < 4; ++i){
      const int co = (((w<<2)+i)<<4) + r15;
      const s16x8 bf = *reinterpret_cast<const s16x8*>(
          wsr + (((((ks<<2)+g)<<8) + co)<<3));
      acc[i] = __builtin_amdgcn_mfma_f32_16x16x32_bf16(af, bf, acc[i], 0, 0, 0);
    }
  }
  float gv[4], bv[4];
#pragma unroll
  for (int i = 0; i < 4; ++i){
    const int co = (((w<<2)+i)<<4) + r15;
    const float sb = srb[co];
    gv[i] = lng[co]; bv[i] = lnb[co];
#pragma unroll
    for (int r = 0; r < 4; ++r) acc[i][r] += sb;
  }
  float s_r[4], q_r[4];
#pragma unroll
  for (int r = 0; r < 4; ++r){
    float s = 0.f, qq = 0.f;
#pragma unroll
    for (int i = 0; i < 4; ++i){ const float v = acc[i][r]; s += v; qq += v*v; }
#pragma unroll
    for (int off = 1; off < 16; off <<= 1){
      s  += __shfl_xor(s, off);
      qq += __shfl_xor(qq, off);
    }
    s_r[r] = s; q_r[r] = qq;
  }
  if (r15 == 0){
#pragma unroll
    for (int r = 0; r < 4; ++r){
      red_s[(g<<2)+r][w] = s_r[r];
      red_q[(g<<2)+r][w] = q_r[r];
    }
  }
  __syncthreads();
  if (tid < 16){
    const float s  = red_s[tid][0]+red_s[tid][1]+red_s[tid][2]+red_s[tid][3];
    const float qq = red_q[tid][0]+red_q[tid][1]+red_q[tid][2]+red_q[tid][3];
    const float mu = s * (1.f/256.f);
    mu_s[tid] = mu;
    rs_s[tid] = rsqrtf(qq*(1.f/256.f) - mu*mu + EPS);
  }
  __syncthreads();
  float mur[4], rsr[4];
#pragma unroll
  for (int r = 0; r < 4; ++r){ mur[r] = mu_s[(g<<2)+r]; rsr[r] = rs_s[(g<<2)+r]; }
#pragma unroll
  for (int i = 0; i < 4; ++i){
    const int co = (((w<<2)+i)<<4) + r15;
#pragma unroll
    for (int r = 0; r < 4; ++r)
      lnxr[(m0+(g<<2)+r)*256 + co] = (acc[i][r]-mur[r])*rsr[r]*gv[i] + bv[i];
  }
}

// ---- K3: depthwise 3x3 KV conv; K row-major [bh,nk,32], V transposed [bh,32,Nk] ----
__global__ __launch_bounds__(512) void k_kvconv(const float* __restrict__ lnxr,
                                                const float* __restrict__ w,
                                                u16* __restrict__ kbuf,
                                                u16* __restrict__ vT){
  const int o = threadIdx.x;         // 0..511
  const int blk = blockIdx.x;        // b*1024 + nk
  const int b = blk >> 10, nk = blk & 1023;
  const int y = nk >> 5, xw = nk & 31;
  const int g = o >> 1;
  float wv[9];
#pragma unroll
  for (int t = 0; t < 9; ++t) wv[t] = w[o*9 + t];
  float acc = 0.f;
#pragma unroll
  for (int ky = 0; ky < 3; ++ky){
    const int yy = y + ky - 1;
    if ((unsigned)yy >= 32u) continue;
#pragma unroll
    for (int kx = 0; kx < 3; ++kx){
      const int xx = xw + kx - 1;
      if ((unsigned)xx >= 32u) continue;
      acc += lnxr[(((b<<10) + (yy<<5) + xx) << 8) + g] * wv[ky*3 + kx];
    }
  }
  const int t = o & 255;
  const int h = t >> 5, dd = t & 31;
  const u16 val = f2b(acc);
  if (o < 256){
    kbuf[(((((b<<3) + h) << 10) + nk) << 5) + dd] = val;
  } else {
    vT[(((((b<<3) + h) << 5) + dd) << 10) + nk] = val;
  }
}

// ---- K4: MFMA flash attention, 64 queries per wave (4 Q-frags), swapped QK^T ----
__global__ __launch_bounds__(256) void k_attn(const u16* __restrict__ q,
                                              const u16* __restrict__ kbuf,
                                              const u16* __restrict__ vT,
                                              u16* __restrict__ attb){
  const int l = threadIdx.x & 63;
  const int w = (blockIdx.x << 2) + (threadIdx.x >> 6);  // 2048 wave-tiles
  const int bh = w >> 6, qt = w & 63;        // 64 q-tiles(64) per (b,h)
  const int b = bh >> 3, h = bh & 7;
  const int r15 = l & 15, g = l >> 4;

  s16x8 qf[4];
#pragma unroll
  for (int qi = 0; qi < 4; ++qi)
    qf[qi] = *reinterpret_cast<const s16x8*>(
        q + (((b<<12) + (qt<<6) + (qi<<4) + r15) << 8) + (h<<5) + (g<<3));

  const u16* kb = kbuf + (bh<<15) + r15*32 + (g<<3);
  const u16* vb = vT + (bh<<15);

  f32x4 acc[4][2];
#pragma unroll
  for (int qi = 0; qi < 4; ++qi){
    acc[qi][0] = (f32x4){0.f,0.f,0.f,0.f};
    acc[qi][1] = (f32x4){0.f,0.f,0.f,0.f};
  }
  const f32x4 zero = {0.f,0.f,0.f,0.f};
  float lsum[4] = {0.f,0.f,0.f,0.f};

  for (int kv0 = 0; kv0 < 1024; kv0 += 64){
    s16x8 kf[4];
#pragma unroll
    for (int st = 0; st < 4; ++st)
      kf[st] = *reinterpret_cast<const s16x8*>(kb + ((kv0 + (st<<4)) << 5));
    s16x8 vf[2][2];
#pragma unroll
    for (int pr = 0; pr < 2; ++pr)
#pragma unroll
      for (int h2 = 0; h2 < 2; ++h2){
        const u16* vrow = vb + (((h2<<4) + r15) << 10) + kv0 + (pr<<5) + (g<<2);
        const s16x4 v0 = *reinterpret_cast<const s16x4*>(vrow);
        const s16x4 v1 = *reinterpret_cast<const s16x4*>(vrow + 16);
        s16x8 vv;
        vv[0]=v0[0]; vv[1]=v0[1]; vv[2]=v0[2]; vv[3]=v0[3];
        vv[4]=v1[0]; vv[5]=v1[1]; vv[6]=v1[2]; vv[7]=v1[3];
        vf[pr][h2] = vv;
      }
#pragma unroll
    for (int qi = 0; qi < 4; ++qi){
      f32x4 s[4];
#pragma unroll
      for (int st = 0; st < 4; ++st)
        s[st] = __builtin_amdgcn_mfma_f32_16x16x32_bf16(kf[st], qf[qi], zero, 0, 0, 0);
      float p[4][4];
      float ps = 0.f;
#pragma unroll
      for (int st = 0; st < 4; ++st)
#pragma unroll
        for (int r = 0; r < 4; ++r){
          const float e = exp2f(s[st][r]);
          p[st][r] = e;
          ps += e;
        }
      ps += __shfl_xor(ps, 16);
      ps += __shfl_xor(ps, 32);
      lsum[qi] += ps;
      s16x8 pf[2];
#pragma unroll
      for (int j = 0; j < 4; ++j){
        pf[0][j]   = f2bq(p[0][j]);
        pf[0][j+4] = f2bq(p[1][j]);
        pf[1][j]   = f2bq(p[2][j]);
        pf[1][j+4] = f2bq(p[3][j]);
      }
#pragma unroll
      for (int pr = 0; pr < 2; ++pr)
#pragma unroll
        for (int h2 = 0; h2 < 2; ++h2)
          acc[qi][h2] = __builtin_amdgcn_mfma_f32_16x16x32_bf16(pf[pr], vf[pr][h2], acc[qi][h2], 0, 0, 0);
    }
  }
#pragma unroll
  for (int qi = 0; qi < 4; ++qi){
    const float linv = 1.f / lsum[qi];
#pragma unroll
    for (int r = 0; r < 4; ++r){
      const float fl = __shfl(linv, (g<<2) + r);
      const int n = (qt<<6) + (qi<<4) + (g<<2) + r;
      u16* orow = attb + (((b<<12) + n) << 8) + (h<<5) + r15;
      orow[0]  = f2b(acc[qi][0][r] * fl);
      orow[16] = f2b(acc[qi][1][r] * fl);
    }
  }
}

// ---- K5: projection as MFMA GEMM (M=16384,N=256,K=256) + bias ----
__global__ __launch_bounds__(256) void k_proj(const u16* __restrict__ attb,
                                              const u16* __restrict__ wpj,
                                              const float* __restrict__ pb,
                                              float* __restrict__ out){
  const int tid = threadIdx.x;
  const int l = tid & 63, w = tid >> 6;
  const int r15 = l & 15, g = l >> 4;
  const int m0 = blockIdx.x << 4;
  f32x4 acc[4];
#pragma unroll
  for (int i = 0; i < 4; ++i) acc[i] = (f32x4){0.f,0.f,0.f,0.f};
  const u16* arow = attb + (m0 + r15)*256 + (g<<3);
#pragma unroll
  for (int ks = 0; ks < 8; ++ks){
    const s16x8 af = *reinterpret_cast<const s16x8*>(arow + (ks<<5));
#pragma unroll
    for (int i = 0; i < 4; ++i){
      const int co = (((w<<2)+i)<<4) + r15;
      const s16x8 bf = *reinterpret_cast<const s16x8*>(
          wpj + (((((ks<<2)+g)<<8) + co)<<3));
      acc[i] = __builtin_amdgcn_mfma_f32_16x16x32_bf16(af, bf, acc[i], 0, 0, 0);
    }
  }
#pragma unroll
  for (int i = 0; i < 4; ++i){
    const int co = (((w<<2)+i)<<4) + r15;
    const float pbv = pb[co];
#pragma unroll
    for (int r = 0; r < 4; ++r)
      out[(m0+(g<<2)+r)*256 + co] = acc[i][r] + pbv;
  }
}

extern "C" void kernel_launch(void* const* d_in, const int* in_sizes, int n_in,
                              void* d_out, int out_size, void* d_ws, size_t ws_size,
                              hipStream_t stream){
  const float* x   = (const float*)d_in[0];
  const float* qw  = (const float*)d_in[1];
  const float* kvw = (const float*)d_in[2];
  const float* srw = (const float*)d_in[3];
  const float* srb = (const float*)d_in[4];
  const float* lng = (const float*)d_in[5];
  const float* lnb = (const float*)d_in[6];
  const float* pw  = (const float*)d_in[7];
  const float* pb  = (const float*)d_in[8];
  float* out = (float*)d_out;

  char* ws = (char*)d_ws;
  u16*   qbuf = (u16*)(ws);                   // 8 MiB  [B,N,C] bf16 (pre-scaled)
  u16*   xbf  = (u16*)(ws + 8388608);         // 8 MiB  [B,N,C] bf16 copy of x
  u16*   attb = (u16*)(ws + 8388608);         // aliases xbf (dead after srgemm)
  float* lnxr = (float*)(ws + 16777216);      // 4 MiB  [B,Nk,C] f32
  u16*   kbuf = (u16*)(ws + 20971520);        // 2 MiB  [bh,Nk,d] bf16
  u16*   vT   = (u16*)(ws + 23068672);        // 2 MiB  [bh,d,Nk] bf16
  u16*   wsr  = (u16*)(ws + 25165824);        // 512 KiB repacked SR weights
  u16*   wpj  = (u16*)(ws + 25690112);        // 128 KiB repacked proj weights

  hipLaunchKernelGGL(k_prep,   dim3(1280),  dim3(256), 0, stream, srw, pw, wsr, wpj);
  hipLaunchKernelGGL(k_qconv,  dim3(16384), dim3(256), 0, stream, x, qw, qbuf, xbf);
  hipLaunchKernelGGL(k_srgemm, dim3(256),   dim3(256), 0, stream, xbf, wsr, srb, lng, lnb, lnxr);
  hipLaunchKernelGGL(k_kvconv, dim3(4096),  dim3(512), 0, stream, lnxr, kvw, kbuf, vT);
  hipLaunchKernelGGL(k_attn,   dim3(512),   dim3(256), 0, stream, qbuf, kbuf, vT, attb);
  hipLaunchKernelGGL(k_proj,   dim3(1024),  dim3(256), 0, stream, attb, wpj, pb, out);
}

// Round 5
// 98.765 us; speedup vs baseline: 12.4964x; 1.3464x over previous
//
#include <hip/hip_runtime.h>
#include <stdint.h>

typedef unsigned short u16;
typedef short s16x8 __attribute__((ext_vector_type(8)));
typedef short s16x4 __attribute__((ext_vector_type(4)));
typedef float f32x4 __attribute__((ext_vector_type(4)));
typedef uint32_t u32x4 __attribute__((ext_vector_type(4)));

#define SCALE 0.17677669529663689f
#define LOG2E 1.4426950408889634f
#define QS (SCALE * LOG2E)
#define EPS 1e-5f

static __device__ __forceinline__ u16 f2b(float f){   // RNE
  uint32_t u = __float_as_uint(f);
  uint32_t r = (u + 0x7FFFu + ((u >> 16) & 1u)) >> 16;
  return (u16)r;
}
static __device__ __forceinline__ uint32_t cvtpk(float lo, float hi){
  uint32_t r;
  asm("v_cvt_pk_bf16_f32 %0, %1, %2" : "=v"(r) : "v"(lo), "v"(hi));
  return r;
}

// ---- K0: repack srw -> wsr [k/8][co][8] bf16 (k=p*256+ci), pw -> wpj same scheme ----
__global__ __launch_bounds__(256) void k_prep(const float* __restrict__ srw,
                                              const float* __restrict__ pw,
                                              u16* __restrict__ wsr,
                                              u16* __restrict__ wpj){
  const int t = blockIdx.x*256 + threadIdx.x;
  if (t < 262144){
    const int co = t >> 10, k = t & 1023;
    const float v = srw[(co<<10) + ((k&255)<<2) + (k>>8)];
    wsr[((((k>>3)<<8) + co)<<3) + (k&7)] = f2b(v);
  } else if (t < 327680){
    const int u2 = t - 262144;
    const int co = u2 >> 8, k = u2 & 255;
    wpj[((((k>>3)<<8) + co)<<3) + (k&7)] = f2b(pw[(co<<8) + k]);
  }
}

// ---- K1: depthwise 3x3 Q conv, 8-px strips; emits bf16 x copy. Q pre-scaled ----
__global__ __launch_bounds__(256) void k_qconv(const float* __restrict__ x,
                                               const float* __restrict__ w,
                                               u16* __restrict__ q,
                                               u16* __restrict__ xbf){
  const int c = threadIdx.x;
  const int blk = blockIdx.x;            // b*512 + y*8 + xs
  const int b = blk >> 9;
  const int y = (blk >> 3) & 63;
  const int x0 = (blk & 7) << 3;
  float wv[9];
#pragma unroll
  for (int t = 0; t < 9; ++t) wv[t] = w[c*9 + t];
  float xin[3][10];
#pragma unroll
  for (int r = 0; r < 3; ++r){
    const int yy = y + r - 1;
    const bool yok = (unsigned)yy < 64u;
#pragma unroll
    for (int j = 0; j < 10; ++j){
      const int xx = x0 + j - 1;
      const bool ok = yok && ((unsigned)xx < 64u);
      xin[r][j] = ok ? x[(((b<<12) + (yy<<6) + xx) << 8) + c] : 0.f;
    }
  }
#pragma unroll
  for (int j = 0; j < 8; ++j){
    float acc = 0.f;
#pragma unroll
    for (int r = 0; r < 3; ++r)
#pragma unroll
      for (int t = 0; t < 3; ++t)
        acc += xin[r][j+t] * wv[r*3 + t];
    const int idx = (((b<<12) + (y<<6) + x0 + j) << 8) + c;
    q[idx]   = f2b(acc * QS);
    xbf[idx] = f2b(xin[1][j+1]);
  }
}

// ---- K2: SR conv as MFMA GEMM (M=4096,N=256,K=1024) + bias + fused LayerNorm ----
__global__ __launch_bounds__(256) void k_srgemm(const u16* __restrict__ xbf,
                                                const u16* __restrict__ wsr,
                                                const float* __restrict__ srb,
                                                const float* __restrict__ lng,
                                                const float* __restrict__ lnb,
                                                float* __restrict__ lnxr){
  __shared__ float red_s[16][4], red_q[16][4];
  __shared__ float mu_s[16], rs_s[16];
  const int tid = threadIdx.x;
  const int l = tid & 63, w = tid >> 6;
  const int r15 = l & 15, g = l >> 4;
  const int m0 = blockIdx.x << 4;
  const int ma = m0 + r15;
  const int bb_ = ma >> 10, nk = ma & 1023;
  const int hs = nk >> 5, wsx = nk & 31;
  int pixbase[4];
#pragma unroll
  for (int p = 0; p < 4; ++p){
    const int y = 2*hs + (p>>1), xx = 2*wsx + (p&1);
    pixbase[p] = (((bb_<<12) + (y<<6) + xx) << 8);
  }
  f32x4 acc[4];
#pragma unroll
  for (int i = 0; i < 4; ++i) acc[i] = (f32x4){0.f,0.f,0.f,0.f};
  for (int ks = 0; ks < 32; ++ks){
    const s16x8 af = *reinterpret_cast<const s16x8*>(
        xbf + pixbase[ks>>3] + ((ks&7)<<5) + (g<<3));
#pragma unroll
    for (int i = 0; i < 4; ++i){
      const int co = (((w<<2)+i)<<4) + r15;
      const s16x8 bf = *reinterpret_cast<const s16x8*>(
          wsr + (((((ks<<2)+g)<<8) + co)<<3));
      acc[i] = __builtin_amdgcn_mfma_f32_16x16x32_bf16(af, bf, acc[i], 0, 0, 0);
    }
  }
  float gv[4], bv[4];
#pragma unroll
  for (int i = 0; i < 4; ++i){
    const int co = (((w<<2)+i)<<4) + r15;
    const float sb = srb[co];
    gv[i] = lng[co]; bv[i] = lnb[co];
#pragma unroll
    for (int r = 0; r < 4; ++r) acc[i][r] += sb;
  }
  float s_r[4], q_r[4];
#pragma unroll
  for (int r = 0; r < 4; ++r){
    float s = 0.f, qq = 0.f;
#pragma unroll
    for (int i = 0; i < 4; ++i){ const float v = acc[i][r]; s += v; qq += v*v; }
#pragma unroll
    for (int off = 1; off < 16; off <<= 1){
      s  += __shfl_xor(s, off);
      qq += __shfl_xor(qq, off);
    }
    s_r[r] = s; q_r[r] = qq;
  }
  if (r15 == 0){
#pragma unroll
    for (int r = 0; r < 4; ++r){
      red_s[(g<<2)+r][w] = s_r[r];
      red_q[(g<<2)+r][w] = q_r[r];
    }
  }
  __syncthreads();
  if (tid < 16){
    const float s  = red_s[tid][0]+red_s[tid][1]+red_s[tid][2]+red_s[tid][3];
    const float qq = red_q[tid][0]+red_q[tid][1]+red_q[tid][2]+red_q[tid][3];
    const float mu = s * (1.f/256.f);
    mu_s[tid] = mu;
    rs_s[tid] = rsqrtf(qq*(1.f/256.f) - mu*mu + EPS);
  }
  __syncthreads();
  float mur[4], rsr[4];
#pragma unroll
  for (int r = 0; r < 4; ++r){ mur[r] = mu_s[(g<<2)+r]; rsr[r] = rs_s[(g<<2)+r]; }
#pragma unroll
  for (int i = 0; i < 4; ++i){
    const int co = (((w<<2)+i)<<4) + r15;
#pragma unroll
    for (int r = 0; r < 4; ++r)
      lnxr[(m0+(g<<2)+r)*256 + co] = (acc[i][r]-mur[r])*rsr[r]*gv[i] + bv[i];
  }
}

// ---- K3: depthwise 3x3 KV conv, 8-px strips; K [bh,nk,32], V [bh,32,Nk] ----
__global__ __launch_bounds__(512) void k_kvconv(const float* __restrict__ lnxr,
                                                const float* __restrict__ w,
                                                u16* __restrict__ kbuf,
                                                u16* __restrict__ vT){
  const int o = threadIdx.x;             // 0..511
  const int blk = blockIdx.x;            // b*128 + y*4 + xs
  const int b = blk >> 7;
  const int y = (blk >> 2) & 31;
  const int x0 = (blk & 3) << 3;
  const int g = o >> 1;
  float wv[9];
#pragma unroll
  for (int t = 0; t < 9; ++t) wv[t] = w[o*9 + t];
  float xin[3][10];
#pragma unroll
  for (int r = 0; r < 3; ++r){
    const int yy = y + r - 1;
    const bool yok = (unsigned)yy < 32u;
#pragma unroll
    for (int j = 0; j < 10; ++j){
      const int xx = x0 + j - 1;
      const bool ok = yok && ((unsigned)xx < 32u);
      xin[r][j] = ok ? lnxr[(((b<<10) + (yy<<5) + xx) << 8) + g] : 0.f;
    }
  }
  float acc[8];
#pragma unroll
  for (int j = 0; j < 8; ++j){
    float a = 0.f;
#pragma unroll
    for (int r = 0; r < 3; ++r)
#pragma unroll
      for (int t = 0; t < 3; ++t)
        a += xin[r][j+t] * wv[r*3 + t];
    acc[j] = a;
  }
  const int t = o & 255;
  const int h = t >> 5, dd = t & 31;
  if (o < 256){
    const int nkbase = (((b<<3) + h) << 10) + (y<<5) + x0;
#pragma unroll
    for (int j = 0; j < 8; ++j)
      kbuf[((nkbase + j) << 5) + dd] = f2b(acc[j]);
  } else {
    s16x8 pack;
#pragma unroll
    for (int j = 0; j < 8; ++j) pack[j] = (short)f2b(acc[j]);
    *reinterpret_cast<s16x8*>(
        vT + (((((b<<3) + h) << 5) + dd) << 10) + (y<<5) + x0) = pack;
  }
}

// ---- K4: MFMA flash attention; 4 waves split the 1024 keys, LDS merge ----
__global__ __launch_bounds__(256) void k_attn(const u16* __restrict__ q,
                                              const u16* __restrict__ kbuf,
                                              const u16* __restrict__ vT,
                                              u16* __restrict__ attb){
  __shared__ float OA[2048], OB[2048];
  __shared__ float lsA[64], lsB[64];
  const int tid = threadIdx.x;
  const int l = tid & 63, w = tid >> 6;
  const int bh = blockIdx.x >> 6, qt = blockIdx.x & 63;
  const int b = bh >> 3, h = bh & 7;
  const int r15 = l & 15, g = l >> 4;

  s16x8 qf[4];
#pragma unroll
  for (int qi = 0; qi < 4; ++qi)
    qf[qi] = *reinterpret_cast<const s16x8*>(
        q + (((b<<12) + (qt<<6) + (qi<<4) + r15) << 8) + (h<<5) + (g<<3));

  const u16* kb = kbuf + (bh<<15) + r15*32 + (g<<3);
  const u16* vb = vT + (bh<<15);
  const int kvbase = w << 8;              // this wave's 256 keys

  f32x4 acc[4][2];
#pragma unroll
  for (int qi = 0; qi < 4; ++qi){
    acc[qi][0] = (f32x4){0.f,0.f,0.f,0.f};
    acc[qi][1] = (f32x4){0.f,0.f,0.f,0.f};
  }
  const f32x4 zero = {0.f,0.f,0.f,0.f};
  float lsum[4] = {0.f,0.f,0.f,0.f};

  for (int t4 = 0; t4 < 4; ++t4){
    const int kv0 = kvbase + (t4<<6);
    s16x8 kf[4];
#pragma unroll
    for (int st = 0; st < 4; ++st)
      kf[st] = *reinterpret_cast<const s16x8*>(kb + ((kv0 + (st<<4)) << 5));
    s16x8 vf[2][2];
#pragma unroll
    for (int pr = 0; pr < 2; ++pr)
#pragma unroll
      for (int h2 = 0; h2 < 2; ++h2){
        const u16* vrow = vb + (((h2<<4) + r15) << 10) + kv0 + (pr<<5) + (g<<2);
        const s16x4 v0 = *reinterpret_cast<const s16x4*>(vrow);
        const s16x4 v1 = *reinterpret_cast<const s16x4*>(vrow + 16);
        s16x8 vv;
        vv[0]=v0[0]; vv[1]=v0[1]; vv[2]=v0[2]; vv[3]=v0[3];
        vv[4]=v1[0]; vv[5]=v1[1]; vv[6]=v1[2]; vv[7]=v1[3];
        vf[pr][h2] = vv;
      }
#pragma unroll
    for (int qi = 0; qi < 4; ++qi){
      f32x4 s[4];
#pragma unroll
      for (int st = 0; st < 4; ++st)
        s[st] = __builtin_amdgcn_mfma_f32_16x16x32_bf16(kf[st], qf[qi], zero, 0, 0, 0);
      float p[4][4];
      float ps = 0.f;
#pragma unroll
      for (int st = 0; st < 4; ++st)
#pragma unroll
        for (int r = 0; r < 4; ++r){
          const float e = __builtin_amdgcn_exp2f(s[st][r]);
          p[st][r] = e;
          ps += e;
        }
      ps += __shfl_xor(ps, 16);
      ps += __shfl_xor(ps, 32);
      lsum[qi] += ps;
      const u32x4 pk0 = {cvtpk(p[0][0],p[0][1]), cvtpk(p[0][2],p[0][3]),
                         cvtpk(p[1][0],p[1][1]), cvtpk(p[1][2],p[1][3])};
      const u32x4 pk1 = {cvtpk(p[2][0],p[2][1]), cvtpk(p[2][2],p[2][3]),
                         cvtpk(p[3][0],p[3][1]), cvtpk(p[3][2],p[3][3])};
      const s16x8 pf0 = __builtin_bit_cast(s16x8, pk0);
      const s16x8 pf1 = __builtin_bit_cast(s16x8, pk1);
#pragma unroll
      for (int h2 = 0; h2 < 2; ++h2){
        acc[qi][h2] = __builtin_amdgcn_mfma_f32_16x16x32_bf16(pf0, vf[0][h2], acc[qi][h2], 0, 0, 0);
        acc[qi][h2] = __builtin_amdgcn_mfma_f32_16x16x32_bf16(pf1, vf[1][h2], acc[qi][h2], 0, 0, 0);
      }
    }
  }
  // merge: w0->OA, w1->OB; then w2 +=OA, w3 +=OB; then combine.
  if (w < 2){
    float* O  = w ? OB  : OA;
    float* ls = w ? lsB : lsA;
#pragma unroll
    for (int qi = 0; qi < 4; ++qi){
#pragma unroll
      for (int h2 = 0; h2 < 2; ++h2)
#pragma unroll
        for (int r = 0; r < 4; ++r)
          O[((qi<<4)+(g<<2)+r)*32 + (h2<<4) + r15] = acc[qi][h2][r];
      if (g == 0) ls[(qi<<4)+r15] = lsum[qi];
    }
  }
  __syncthreads();
  if (w >= 2){
    float* O  = (w&1) ? OB  : OA;
    float* ls = (w&1) ? lsB : lsA;
#pragma unroll
    for (int qi = 0; qi < 4; ++qi){
#pragma unroll
      for (int h2 = 0; h2 < 2; ++h2)
#pragma unroll
        for (int r = 0; r < 4; ++r)
          O[((qi<<4)+(g<<2)+r)*32 + (h2<<4) + r15] += acc[qi][h2][r];
      if (g == 0) ls[(qi<<4)+r15] += lsum[qi];
    }
  }
  __syncthreads();
  const int qloc = tid >> 2;
  const int d0 = (tid & 3) << 3;
  const float linv = 1.f / (lsA[qloc] + lsB[qloc]);
  s16x8 outp;
#pragma unroll
  for (int i = 0; i < 8; ++i)
    outp[i] = (short)f2b((OA[qloc*32 + d0 + i] + OB[qloc*32 + d0 + i]) * linv);
  *reinterpret_cast<s16x8*>(
      attb + (((b<<12) + (qt<<6) + qloc) << 8) + (h<<5) + d0) = outp;
}

// ---- K5: projection as MFMA GEMM (M=16384,N=256,K=256) + bias ----
__global__ __launch_bounds__(256) void k_proj(const u16* __restrict__ attb,
                                              const u16* __restrict__ wpj,
                                              const float* __restrict__ pb,
                                              float* __restrict__ out){
  const int tid = threadIdx.x;
  const int l = tid & 63, w = tid >> 6;
  const int r15 = l & 15, g = l >> 4;
  const int m0 = blockIdx.x << 4;
  f32x4 acc[4];
#pragma unroll
  for (int i = 0; i < 4; ++i) acc[i] = (f32x4){0.f,0.f,0.f,0.f};
  const u16* arow = attb + (m0 + r15)*256 + (g<<3);
#pragma unroll
  for (int ks = 0; ks < 8; ++ks){
    const s16x8 af = *reinterpret_cast<const s16x8*>(arow + (ks<<5));
#pragma unroll
    for (int i = 0; i < 4; ++i){
      const int co = (((w<<2)+i)<<4) + r15;
      const s16x8 bf = *reinterpret_cast<const s16x8*>(
          wpj + (((((ks<<2)+g)<<8) + co)<<3));
      acc[i] = __builtin_amdgcn_mfma_f32_16x16x32_bf16(af, bf, acc[i], 0, 0, 0);
    }
  }
#pragma unroll
  for (int i = 0; i < 4; ++i){
    const int co = (((w<<2)+i)<<4) + r15;
    const float pbv = pb[co];
#pragma unroll
    for (int r = 0; r < 4; ++r)
      out[(m0+(g<<2)+r)*256 + co] = acc[i][r] + pbv;
  }
}

extern "C" void kernel_launch(void* const* d_in, const int* in_sizes, int n_in,
                              void* d_out, int out_size, void* d_ws, size_t ws_size,
                              hipStream_t stream){
  const float* x   = (const float*)d_in[0];
  const float* qw  = (const float*)d_in[1];
  const float* kvw = (const float*)d_in[2];
  const float* srw = (const float*)d_in[3];
  const float* srb = (const float*)d_in[4];
  const float* lng = (const float*)d_in[5];
  const float* lnb = (const float*)d_in[6];
  const float* pw  = (const float*)d_in[7];
  const float* pb  = (const float*)d_in[8];
  float* out = (float*)d_out;

  char* ws = (char*)d_ws;
  u16*   qbuf = (u16*)(ws);                   // 8 MiB  [B,N,C] bf16 (pre-scaled)
  u16*   xbf  = (u16*)(ws + 8388608);         // 8 MiB  [B,N,C] bf16 copy of x
  u16*   attb = (u16*)(ws + 8388608);         // aliases xbf (dead after srgemm)
  float* lnxr = (float*)(ws + 16777216);      // 4 MiB  [B,Nk,C] f32
  u16*   kbuf = (u16*)(ws + 20971520);        // 2 MiB  [bh,Nk,d] bf16
  u16*   vT   = (u16*)(ws + 23068672);        // 2 MiB  [bh,d,Nk] bf16
  u16*   wsr  = (u16*)(ws + 25165824);        // 512 KiB repacked SR weights
  u16*   wpj  = (u16*)(ws + 25690112);        // 128 KiB repacked proj weights

  hipLaunchKernelGGL(k_prep,   dim3(1280), dim3(256), 0, stream, srw, pw, wsr, wpj);
  hipLaunchKernelGGL(k_qconv,  dim3(2048), dim3(256), 0, stream, x, qw, qbuf, xbf);
  hipLaunchKernelGGL(k_srgemm, dim3(256),  dim3(256), 0, stream, xbf, wsr, srb, lng, lnb, lnxr);
  hipLaunchKernelGGL(k_kvconv, dim3(512),  dim3(512), 0, stream, lnxr, kvw, kbuf, vT);
  hipLaunchKernelGGL(k_attn,   dim3(2048), dim3(256), 0, stream, qbuf, kbuf, vT, attb);
  hipLaunchKernelGGL(k_proj,   dim3(1024), dim3(256), 0, stream, attb, wpj, pb, out);
}

// Round 6
// 86.831 us; speedup vs baseline: 14.2140x; 1.1374x over previous
//
#include <hip/hip_runtime.h>
#include <stdint.h>

typedef unsigned short u16;
typedef short s16x8 __attribute__((ext_vector_type(8)));
typedef short s16x4 __attribute__((ext_vector_type(4)));
typedef float f32x4 __attribute__((ext_vector_type(4)));
typedef uint32_t u32x4 __attribute__((ext_vector_type(4)));

#define SCALE 0.17677669529663689f
#define LOG2E 1.4426950408889634f
#define QS (SCALE * LOG2E)
#define EPS 1e-5f

static __device__ __forceinline__ float b2f(u16 u){
  union { uint32_t i; float f; } cv; cv.i = ((uint32_t)u) << 16; return cv.f;
}
static __device__ __forceinline__ u16 f2b(float f){   // RNE
  uint32_t u = __float_as_uint(f);
  uint32_t r = (u + 0x7FFFu + ((u >> 16) & 1u)) >> 16;
  return (u16)r;
}
static __device__ __forceinline__ uint32_t cvtpk(float lo, float hi){
  uint32_t r;
  asm("v_cvt_pk_bf16_f32 %0, %1, %2" : "=v"(r) : "v"(lo), "v"(hi));
  return r;
}

// ---- K0: cast x->bf16 + repack srw/pw into B-frag order ----
__global__ __launch_bounds__(256) void k_prep(const float* __restrict__ x,
                                              const float* __restrict__ srw,
                                              const float* __restrict__ pw,
                                              u16* __restrict__ xbf,
                                              u16* __restrict__ wsr,
                                              u16* __restrict__ wpj){
  const int t = blockIdx.x*256 + threadIdx.x;
  if (t < 1048576){
    const float4 xv = ((const float4*)x)[t];
    ushort4 o;
    o.x = f2b(xv.x); o.y = f2b(xv.y); o.z = f2b(xv.z); o.w = f2b(xv.w);
    ((ushort4*)xbf)[t] = o;
  } else if (t < 1310720){
    const int t2 = t - 1048576;
    const int co = t2 >> 10, k = t2 & 1023;
    const float v = srw[(co<<10) + ((k&255)<<2) + (k>>8)];
    wsr[((((k>>3)<<8) + co)<<3) + (k&7)] = f2b(v);
  } else {
    const int t3 = t - 1310720;
    const int co = t3 >> 8, k = t3 & 255;
    wpj[((((k>>3)<<8) + co)<<3) + (k&7)] = f2b(pw[(co<<8) + k]);
  }
}

// ---- K1: depthwise 3x3 Q conv from bf16 x, 8-px strips; Q pre-scaled ----
__global__ __launch_bounds__(256) void k_qconv(const u16* __restrict__ xbf,
                                               const float* __restrict__ w,
                                               u16* __restrict__ q){
  const int c = threadIdx.x;
  const int blk = blockIdx.x;            // b*512 + y*8 + xs
  const int b = blk >> 9;
  const int y = (blk >> 3) & 63;
  const int x0 = (blk & 7) << 3;
  float wv[9];
#pragma unroll
  for (int t = 0; t < 9; ++t) wv[t] = w[c*9 + t];
  float xin[3][10];
#pragma unroll
  for (int r = 0; r < 3; ++r){
    const int yy = y + r - 1;
    const bool yok = (unsigned)yy < 64u;
#pragma unroll
    for (int j = 0; j < 10; ++j){
      const int xx = x0 + j - 1;
      const bool ok = yok && ((unsigned)xx < 64u);
      xin[r][j] = ok ? b2f(xbf[(((b<<12) + (yy<<6) + xx) << 8) + c]) : 0.f;
    }
  }
#pragma unroll
  for (int j = 0; j < 8; ++j){
    float acc = 0.f;
#pragma unroll
    for (int r = 0; r < 3; ++r)
#pragma unroll
      for (int t = 0; t < 3; ++t)
        acc += xin[r][j+t] * wv[r*3 + t];
    q[(((b<<12) + (y<<6) + x0 + j) << 8) + c] = f2b(acc * QS);
  }
}

// ---- K2: SR conv as MFMA GEMM (M=4096,N=256,K=1024) + bias + fused LayerNorm ----
__global__ __launch_bounds__(256) void k_srgemm(const u16* __restrict__ xbf,
                                                const u16* __restrict__ wsr,
                                                const float* __restrict__ srb,
                                                const float* __restrict__ lng,
                                                const float* __restrict__ lnb,
                                                float* __restrict__ lnxr){
  __shared__ float red_s[16][4], red_q[16][4];
  __shared__ float mu_s[16], rs_s[16];
  const int tid = threadIdx.x;
  const int l = tid & 63, w = tid >> 6;
  const int r15 = l & 15, g = l >> 4;
  const int m0 = blockIdx.x << 4;
  const int ma = m0 + r15;
  const int bb_ = ma >> 10, nk = ma & 1023;
  const int hs = nk >> 5, wsx = nk & 31;
  int pixbase[4];
#pragma unroll
  for (int p = 0; p < 4; ++p){
    const int y = 2*hs + (p>>1), xx = 2*wsx + (p&1);
    pixbase[p] = (((bb_<<12) + (y<<6) + xx) << 8);
  }
  f32x4 acc[4];
#pragma unroll
  for (int i = 0; i < 4; ++i) acc[i] = (f32x4){0.f,0.f,0.f,0.f};
  for (int ks = 0; ks < 32; ++ks){
    const s16x8 af = *reinterpret_cast<const s16x8*>(
        xbf + pixbase[ks>>3] + ((ks&7)<<5) + (g<<3));
#pragma unroll
    for (int i = 0; i < 4; ++i){
      const int co = (((w<<2)+i)<<4) + r15;
      const s16x8 bf = *reinterpret_cast<const s16x8*>(
          wsr + (((((ks<<2)+g)<<8) + co)<<3));
      acc[i] = __builtin_amdgcn_mfma_f32_16x16x32_bf16(af, bf, acc[i], 0, 0, 0);
    }
  }
  float gv[4], bv[4];
#pragma unroll
  for (int i = 0; i < 4; ++i){
    const int co = (((w<<2)+i)<<4) + r15;
    const float sb = srb[co];
    gv[i] = lng[co]; bv[i] = lnb[co];
#pragma unroll
    for (int r = 0; r < 4; ++r) acc[i][r] += sb;
  }
  float s_r[4], q_r[4];
#pragma unroll
  for (int r = 0; r < 4; ++r){
    float s = 0.f, qq = 0.f;
#pragma unroll
    for (int i = 0; i < 4; ++i){ const float v = acc[i][r]; s += v; qq += v*v; }
#pragma unroll
    for (int off = 1; off < 16; off <<= 1){
      s  += __shfl_xor(s, off);
      qq += __shfl_xor(qq, off);
    }
    s_r[r] = s; q_r[r] = qq;
  }
  if (r15 == 0){
#pragma unroll
    for (int r = 0; r < 4; ++r){
      red_s[(g<<2)+r][w] = s_r[r];
      red_q[(g<<2)+r][w] = q_r[r];
    }
  }
  __syncthreads();
  if (tid < 16){
    const float s  = red_s[tid][0]+red_s[tid][1]+red_s[tid][2]+red_s[tid][3];
    const float qq = red_q[tid][0]+red_q[tid][1]+red_q[tid][2]+red_q[tid][3];
    const float mu = s * (1.f/256.f);
    mu_s[tid] = mu;
    rs_s[tid] = rsqrtf(qq*(1.f/256.f) - mu*mu + EPS);
  }
  __syncthreads();
  float mur[4], rsr[4];
#pragma unroll
  for (int r = 0; r < 4; ++r){ mur[r] = mu_s[(g<<2)+r]; rsr[r] = rs_s[(g<<2)+r]; }
#pragma unroll
  for (int i = 0; i < 4; ++i){
    const int co = (((w<<2)+i)<<4) + r15;
#pragma unroll
    for (int r = 0; r < 4; ++r)
      lnxr[(m0+(g<<2)+r)*256 + co] = (acc[i][r]-mur[r])*rsr[r]*gv[i] + bv[i];
  }
}

// ---- K3: depthwise 3x3 KV conv, 8-px strips; K [bh,nk,32], V [bh,32,Nk] (V block-swizzled) ----
__global__ __launch_bounds__(512) void k_kvconv(const float* __restrict__ lnxr,
                                                const float* __restrict__ w,
                                                u16* __restrict__ kbuf,
                                                u16* __restrict__ vT){
  const int o = threadIdx.x;             // 0..511
  const int blk = blockIdx.x;            // b*128 + y*4 + xs
  const int b = blk >> 7;
  const int y = (blk >> 2) & 31;
  const int x0 = (blk & 3) << 3;
  const int g = o >> 1;
  float wv[9];
#pragma unroll
  for (int t = 0; t < 9; ++t) wv[t] = w[o*9 + t];
  float xin[3][10];
#pragma unroll
  for (int r = 0; r < 3; ++r){
    const int yy = y + r - 1;
    const bool yok = (unsigned)yy < 32u;
#pragma unroll
    for (int j = 0; j < 10; ++j){
      const int xx = x0 + j - 1;
      const bool ok = yok && ((unsigned)xx < 32u);
      xin[r][j] = ok ? lnxr[(((b<<10) + (yy<<5) + xx) << 8) + g] : 0.f;
    }
  }
  float acc[8];
#pragma unroll
  for (int j = 0; j < 8; ++j){
    float a = 0.f;
#pragma unroll
    for (int r = 0; r < 3; ++r)
#pragma unroll
      for (int t = 0; t < 3; ++t)
        a += xin[r][j+t] * wv[r*3 + t];
    acc[j] = a;
  }
  const int t = o & 255;
  const int h = t >> 5, dd = t & 31;
  if (o < 256){
    const int nkbase = (((b<<3) + h) << 10) + (y<<5) + x0;
#pragma unroll
    for (int j = 0; j < 8; ++j)
      kbuf[((nkbase + j) << 5) + dd] = f2b(acc[j]);
  } else {
    s16x8 pack;
#pragma unroll
    for (int j = 0; j < 8; ++j) pack[j] = (short)f2b(acc[j]);
    const int col0 = (y<<5) + x0;
    const int colS = (((col0>>3) ^ (dd&7)) << 3);   // 16B-block XOR swizzle
    *reinterpret_cast<s16x8*>(
        vT + (((((b<<3) + h) << 5) + dd) << 10) + colS) = pack;
  }
}

// ---- K4: MFMA flash attention; whole-head K/V resident in LDS ----
// 256 blocks x 512 thr; block = (b,h, 512-query chunk); 8 waves x 64 queries
__global__ __launch_bounds__(512) void k_attn(const u16* __restrict__ q,
                                              const u16* __restrict__ kbuf,
                                              const u16* __restrict__ vT,
                                              u16* __restrict__ attb){
  __shared__ __align__(16) u16 KL[32768];   // [nk][32]
  __shared__ __align__(16) u16 VL[32768];   // [d][1024], 16B blocks swizzled by d&7
  const int tid = threadIdx.x;
  const int l = tid & 63, w = tid >> 6;
  const int i = blockIdx.x;
  const int xcd = i & 7, slot = i >> 3;
  const int bh = (xcd<<2) + (slot>>3);      // 4 heads per XCD cluster
  const int chunk = slot & 7;
  const int b = bh >> 3, h = bh & 7;
  const int r15 = l & 15, g = l >> 4;
  const int n0 = (chunk<<9) + (w<<6);       // this wave's 64 queries

  {
    const uint4* kg = (const uint4*)(kbuf + (bh<<15));
    const uint4* vg = (const uint4*)(vT   + (bh<<15));
    uint4* kl = (uint4*)KL;
    uint4* vl = (uint4*)VL;
#pragma unroll
    for (int r = 0; r < 8; ++r){
      kl[(r<<9) + tid] = kg[(r<<9) + tid];
      vl[(r<<9) + tid] = vg[(r<<9) + tid];
    }
  }
  __syncthreads();

  s16x8 qf[4];
#pragma unroll
  for (int qi = 0; qi < 4; ++qi)
    qf[qi] = *reinterpret_cast<const s16x8*>(
        q + (((b<<12) + n0 + (qi<<4) + r15) << 8) + (h<<5) + (g<<3));

  f32x4 acc[4][2];
#pragma unroll
  for (int qi = 0; qi < 4; ++qi){
    acc[qi][0] = (f32x4){0.f,0.f,0.f,0.f};
    acc[qi][1] = (f32x4){0.f,0.f,0.f,0.f};
  }
  const f32x4 zero = {0.f,0.f,0.f,0.f};
  float lsum[4] = {0.f,0.f,0.f,0.f};
  const int vswz = (r15 & 7);

  for (int kv0 = 0; kv0 < 1024; kv0 += 64){
    s16x8 kf[4];
#pragma unroll
    for (int st = 0; st < 4; ++st)
      kf[st] = *reinterpret_cast<const s16x8*>(
          KL + ((kv0 + (st<<4) + r15) << 5) + (g<<3));
    s16x8 vf[2][2];
#pragma unroll
    for (int pr = 0; pr < 2; ++pr)
#pragma unroll
      for (int h2 = 0; h2 < 2; ++h2){
        const int cl  = kv0 + (pr<<5) + (g<<2);
        const int cl2 = cl + 16;
        const int rb  = ((h2<<4) + r15) << 10;
        const s16x4 v0 = *reinterpret_cast<const s16x4*>(
            VL + rb + (((cl >>3) ^ vswz) << 3) + (cl &7));
        const s16x4 v1 = *reinterpret_cast<const s16x4*>(
            VL + rb + (((cl2>>3) ^ vswz) << 3) + (cl2&7));
        s16x8 vv;
        vv[0]=v0[0]; vv[1]=v0[1]; vv[2]=v0[2]; vv[3]=v0[3];
        vv[4]=v1[0]; vv[5]=v1[1]; vv[6]=v1[2]; vv[7]=v1[3];
        vf[pr][h2] = vv;
      }
#pragma unroll
    for (int qi = 0; qi < 4; ++qi){
      f32x4 s[4];
      __builtin_amdgcn_s_setprio(1);
#pragma unroll
      for (int st = 0; st < 4; ++st)
        s[st] = __builtin_amdgcn_mfma_f32_16x16x32_bf16(kf[st], qf[qi], zero, 0, 0, 0);
      __builtin_amdgcn_s_setprio(0);
      float p[4][4];
      float ps = 0.f;
#pragma unroll
      for (int st = 0; st < 4; ++st)
#pragma unroll
        for (int r = 0; r < 4; ++r){
          const float e = __builtin_amdgcn_exp2f(s[st][r]);
          p[st][r] = e;
          ps += e;
        }
      ps += __shfl_xor(ps, 16);
      ps += __shfl_xor(ps, 32);
      lsum[qi] += ps;
      const u32x4 pk0 = {cvtpk(p[0][0],p[0][1]), cvtpk(p[0][2],p[0][3]),
                         cvtpk(p[1][0],p[1][1]), cvtpk(p[1][2],p[1][3])};
      const u32x4 pk1 = {cvtpk(p[2][0],p[2][1]), cvtpk(p[2][2],p[2][3]),
                         cvtpk(p[3][0],p[3][1]), cvtpk(p[3][2],p[3][3])};
      const s16x8 pf0 = __builtin_bit_cast(s16x8, pk0);
      const s16x8 pf1 = __builtin_bit_cast(s16x8, pk1);
      __builtin_amdgcn_s_setprio(1);
#pragma unroll
      for (int h2 = 0; h2 < 2; ++h2){
        acc[qi][h2] = __builtin_amdgcn_mfma_f32_16x16x32_bf16(pf0, vf[0][h2], acc[qi][h2], 0, 0, 0);
        acc[qi][h2] = __builtin_amdgcn_mfma_f32_16x16x32_bf16(pf1, vf[1][h2], acc[qi][h2], 0, 0, 0);
      }
      __builtin_amdgcn_s_setprio(0);
    }
  }
#pragma unroll
  for (int qi = 0; qi < 4; ++qi){
    const float linv = 1.f / lsum[qi];
#pragma unroll
    for (int r = 0; r < 4; ++r){
      const float fl = __shfl(linv, (g<<2) + r);
      const int n = n0 + (qi<<4) + (g<<2) + r;
      u16* orow = attb + (((b<<12) + n) << 8) + (h<<5) + r15;
      orow[0]  = f2b(acc[qi][0][r] * fl);
      orow[16] = f2b(acc[qi][1][r] * fl);
    }
  }
}

// ---- K5: projection as MFMA GEMM (M=16384,N=256,K=256) + bias ----
__global__ __launch_bounds__(256) void k_proj(const u16* __restrict__ attb,
                                              const u16* __restrict__ wpj,
                                              const float* __restrict__ pb,
                                              float* __restrict__ out){
  const int tid = threadIdx.x;
  const int l = tid & 63, w = tid >> 6;
  const int r15 = l & 15, g = l >> 4;
  const int m0 = blockIdx.x << 4;
  f32x4 acc[4];
#pragma unroll
  for (int i = 0; i < 4; ++i) acc[i] = (f32x4){0.f,0.f,0.f,0.f};
  const u16* arow = attb + (m0 + r15)*256 + (g<<3);
#pragma unroll
  for (int ks = 0; ks < 8; ++ks){
    const s16x8 af = *reinterpret_cast<const s16x8*>(arow + (ks<<5));
#pragma unroll
    for (int i = 0; i < 4; ++i){
      const int co = (((w<<2)+i)<<4) + r15;
      const s16x8 bf = *reinterpret_cast<const s16x8*>(
          wpj + (((((ks<<2)+g)<<8) + co)<<3));
      acc[i] = __builtin_amdgcn_mfma_f32_16x16x32_bf16(af, bf, acc[i], 0, 0, 0);
    }
  }
#pragma unroll
  for (int i = 0; i < 4; ++i){
    const int co = (((w<<2)+i)<<4) + r15;
    const float pbv = pb[co];
#pragma unroll
    for (int r = 0; r < 4; ++r)
      out[(m0+(g<<2)+r)*256 + co] = acc[i][r] + pbv;
  }
}

extern "C" void kernel_launch(void* const* d_in, const int* in_sizes, int n_in,
                              void* d_out, int out_size, void* d_ws, size_t ws_size,
                              hipStream_t stream){
  const float* x   = (const float*)d_in[0];
  const float* qw  = (const float*)d_in[1];
  const float* kvw = (const float*)d_in[2];
  const float* srw = (const float*)d_in[3];
  const float* srb = (const float*)d_in[4];
  const float* lng = (const float*)d_in[5];
  const float* lnb = (const float*)d_in[6];
  const float* pw  = (const float*)d_in[7];
  const float* pb  = (const float*)d_in[8];
  float* out = (float*)d_out;

  char* ws = (char*)d_ws;
  u16*   qbuf = (u16*)(ws);                   // 8 MiB  [B,N,C] bf16 (pre-scaled)
  u16*   xbf  = (u16*)(ws + 8388608);         // 8 MiB  [B,N,C] bf16 copy of x
  u16*   attb = (u16*)(ws + 8388608);         // aliases xbf (dead after srgemm/qconv)
  float* lnxr = (float*)(ws + 16777216);      // 4 MiB  [B,Nk,C] f32
  u16*   kbuf = (u16*)(ws + 20971520);        // 2 MiB  [bh,Nk,d] bf16
  u16*   vT   = (u16*)(ws + 23068672);        // 2 MiB  [bh,d,Nk] bf16 (swizzled)
  u16*   wsr  = (u16*)(ws + 25165824);        // 512 KiB repacked SR weights
  u16*   wpj  = (u16*)(ws + 25690112);        // 128 KiB repacked proj weights

  hipLaunchKernelGGL(k_prep,   dim3(5376), dim3(256), 0, stream, x, srw, pw, xbf, wsr, wpj);
  hipLaunchKernelGGL(k_qconv,  dim3(2048), dim3(256), 0, stream, xbf, qw, qbuf);
  hipLaunchKernelGGL(k_srgemm, dim3(256),  dim3(256), 0, stream, xbf, wsr, srb, lng, lnb, lnxr);
  hipLaunchKernelGGL(k_kvconv, dim3(512),  dim3(512), 0, stream, lnxr, kvw, kbuf, vT);
  hipLaunchKernelGGL(k_attn,   dim3(256),  dim3(512), 0, stream, qbuf, kbuf, vT, attb);
  hipLaunchKernelGGL(k_proj,   dim3(1024), dim3(256), 0, stream, attb, wpj, pb, out);
}